// Round 11
// baseline (3300.299 us; speedup 1.0000x reference)
//
#include <hip/hip_runtime.h>

// Problem constants
#define Bb 16
#define Nn_ 576
#define Cc 1024
#define Hh 16
#define HD 64
#define HID 4096
#define AVAIL 832   // CUR(256) + N(576)
#define ROWS (Bb*Nn_)  // 9216

typedef __bf16 bf16x8 __attribute__((ext_vector_type(8)));
typedef float f32x4 __attribute__((ext_vector_type(4)));

__device__ __forceinline__ unsigned short f2bf(float f) {
  unsigned u = __float_as_uint(f);
  u += 0x7FFF + ((u >> 16) & 1);
  return (unsigned short)(u >> 16);
}

__device__ __forceinline__ void glds16(const void* g, void* l) {
  __builtin_amdgcn_global_load_lds(
      (const __attribute__((address_space(1))) void*)g,
      (__attribute__((address_space(3))) void*)l, 16, 0, 0);
}

__device__ __forceinline__ bf16x8 ds_read128(const void* p) {
  bf16x8 r;
  asm volatile("ds_read_b128 %0, %1"
               : "=v"(r)
               : "v"((const __attribute__((address_space(3))) char*)p));
  return r;
}

#define BARR() asm volatile("s_barrier" ::: "memory")
#define VMCNT4() asm volatile("s_waitcnt vmcnt(4)" ::: "memory")
#define VMCNT0() asm volatile("s_waitcnt vmcnt(0)" ::: "memory")
#define LGKM0() asm volatile("s_waitcnt lgkmcnt(0)" ::: "memory")
#define SCHEDB() __builtin_amdgcn_sched_barrier(0)

// ---------------- weight convert + transpose: in [K][N] f32 -> out [N][K] bf16
__global__ void wtrans_k(const float* __restrict__ in, unsigned short* __restrict__ out,
                         int K, int N) {
  __shared__ float tile[32][33];
  int k0 = blockIdx.x * 32, n0 = blockIdx.y * 32;
  int tx = threadIdx.x, ty = threadIdx.y;  // 32 x 8
#pragma unroll
  for (int i = 0; i < 4; i++)
    tile[ty + i * 8][tx] = in[(size_t)(k0 + ty + i * 8) * N + n0 + tx];
  __syncthreads();
#pragma unroll
  for (int i = 0; i < 4; i++)
    out[(size_t)(n0 + ty + i * 8) * K + k0 + tx] = f2bf(tile[tx][ty + i * 8]);
}

// ---------------- LayerNorm f32 -> bf16, one block per row of 1024
__global__ void ln_k(const float* __restrict__ x, const float* __restrict__ w,
                     const float* __restrict__ bi, unsigned short* __restrict__ out) {
  int row = blockIdx.x;
  int t = threadIdx.x;
  float4 v = ((const float4*)(x + (size_t)row * Cc))[t];
  float s = v.x + v.y + v.z + v.w;
  float s2 = v.x * v.x + v.y * v.y + v.z * v.z + v.w * v.w;
#pragma unroll
  for (int off = 1; off < 64; off <<= 1) { s += __shfl_xor(s, off); s2 += __shfl_xor(s2, off); }
  __shared__ float red[8];
  int wid = t >> 6, lane = t & 63;
  if (lane == 0) { red[wid] = s; red[4 + wid] = s2; }
  __syncthreads();
  s = red[0] + red[1] + red[2] + red[3];
  s2 = red[4] + red[5] + red[6] + red[7];
  float mean = s * (1.0f / Cc);
  float var = s2 * (1.0f / Cc) - mean * mean;
  float rstd = rsqrtf(var + 1e-5f);
  float4 wv = ((const float4*)w)[t];
  float4 bv = ((const float4*)bi)[t];
  ushort4 ov;
  ov.x = f2bf((v.x - mean) * rstd * wv.x + bv.x);
  ov.y = f2bf((v.y - mean) * rstd * wv.y + bv.y);
  ov.z = f2bf((v.z - mean) * rstd * wv.z + bv.z);
  ov.w = f2bf((v.w - mean) * rstd * wv.w + bv.w);
  *(ushort4*)(out + (size_t)row * Cc + t * 4) = ov;
}

// ---------------- 256x256 8-wave pipelined GEMM (R6 structure), 128KB LDS dbuf.
// EPI: 0 bf16, 1 gelu->bf16, 2 f32+resid
template <int EPI>
__global__ __launch_bounds__(512, 2) void gemm8_k(
    const unsigned short* __restrict__ A, const unsigned short* __restrict__ Bt,
    const float* __restrict__ bias, const float* __restrict__ resid,
    void* __restrict__ outv, int N, int K) {
  extern __shared__ __align__(16) char smem[];
  char* A0buf = smem;
  char* B0buf = smem + 32768;
  char* A1buf = smem + 65536;
  char* B1buf = smem + 98304;

  const int tid = threadIdx.x, lane = tid & 63, wid = tid >> 6;
  const int wr = wid >> 2, wc = wid & 3;
  const int l15 = lane & 15, l4 = lane >> 4;
  const int m0 = blockIdx.x * 256, n0 = blockIdx.y * 256;
  const int KT = K >> 6;
  const size_t K2 = (size_t)K * 2;

  const int toff = (tid >> 3) * (int)K2 + ((((tid & 7) ^ ((tid >> 3) & 7)) << 4));
  const char* As0 = (const char*)A + (size_t)m0 * K2 + toff;
  const char* As1 = As0 + 128 * K2;
  const char* Bs0 = (const char*)Bt + (size_t)n0 * K2 + toff;
  const char* Bs1 = Bs0 + 128 * K2;
  const size_t l64 = 64 * K2;
  const int dst = tid * 16;

  const int s0 = ((l4 ^ (l15 & 7)) << 4);
  const int rbA = (wr * 128 + l15) * 128;
  const int rbB = (wc * 64 + l15) * 128;

  f32x4 acc[2][2][4][2] = {};
  bf16x8 a0[4][2], a1[4][2], bb0[2][2], bb1[2][2];

#define STAGE(srcH, ktb, ldsT, half)                        \
  do {                                                      \
    const char* _g = (srcH) + (size_t)(ktb);                \
    glds16(_g, (ldsT) + (half) * 16384 + dst);              \
    glds16(_g + l64, (ldsT) + (half) * 16384 + 8192 + dst); \
  } while (0)

#define RD_A(dA, CA, mh)                                                           \
  _Pragma("unroll") for (int mi = 0; mi < 4; ++mi)                                 \
  _Pragma("unroll") for (int ks = 0; ks < 2; ++ks)                                 \
    dA[mi][ks] = ds_read128((CA) + rbA + (mh) * 8192 + mi * 2048 + (s0 ^ (ks << 6)));

#define RD_B(dB, CB, nh)                                                           \
  _Pragma("unroll") for (int ni = 0; ni < 2; ++ni)                                 \
  _Pragma("unroll") for (int ks = 0; ks < 2; ++ks)                                 \
    dB[ni][ks] = ds_read128((CB) + rbB + (nh) * 4096 + ni * 2048 + (s0 ^ (ks << 6)));

#define MF(mh, nh, av, bv)                                                         \
  _Pragma("unroll") for (int mi = 0; mi < 4; ++mi)                                 \
  _Pragma("unroll") for (int ni = 0; ni < 2; ++ni)                                 \
  _Pragma("unroll") for (int ks = 0; ks < 2; ++ks)                                 \
    acc[mh][nh][mi][ni] = __builtin_amdgcn_mfma_f32_16x16x32_bf16(                 \
        av[mi][ks], bv[ni][ks], acc[mh][nh][mi][ni], 0, 0, 0);

#define TILE(CA, CB, OA, OB, t)                                       \
  do {                                                                \
    const size_t kt1 = (size_t)((t) + 1) * 128;                       \
    const size_t kt2 = (size_t)((t) + 2) * 128;                       \
    RD_A(a0, CA, 0); RD_B(bb0, CB, 0);                                \
    STAGE(Bs1, kt1, OB, 1);                                           \
    BARR(); LGKM0(); SCHEDB();                                        \
    __builtin_amdgcn_s_setprio(1); MF(0, 0, a0, bb0);                 \
    __builtin_amdgcn_s_setprio(0); BARR();                            \
    RD_B(bb1, CB, 1);                                                 \
    STAGE(As1, kt1, OA, 1);                                           \
    BARR(); LGKM0(); SCHEDB();                                        \
    __builtin_amdgcn_s_setprio(1); MF(0, 1, a0, bb1);                 \
    __builtin_amdgcn_s_setprio(0); BARR();                            \
    RD_A(a1, CA, 1);                                                  \
    STAGE(Bs0, kt2, CB, 0);                                           \
    BARR(); LGKM0(); SCHEDB();                                        \
    __builtin_amdgcn_s_setprio(1); MF(1, 0, a1, bb0);                 \
    __builtin_amdgcn_s_setprio(0); BARR();                            \
    STAGE(As0, kt2, CA, 0);                                           \
    VMCNT4(); BARR();                                                 \
    __builtin_amdgcn_s_setprio(1); MF(1, 1, a1, bb1);                 \
    __builtin_amdgcn_s_setprio(0); BARR();                            \
  } while (0)

#define TILE_T1(CA, CB, OA, OB, t)                                    \
  do {                                                                \
    const size_t kt1 = (size_t)((t) + 1) * 128;                       \
    RD_A(a0, CA, 0); RD_B(bb0, CB, 0);                                \
    STAGE(Bs1, kt1, OB, 1);                                           \
    BARR(); LGKM0(); SCHEDB();                                        \
    __builtin_amdgcn_s_setprio(1); MF(0, 0, a0, bb0);                 \
    __builtin_amdgcn_s_setprio(0); BARR();                            \
    RD_B(bb1, CB, 1);                                                 \
    STAGE(As1, kt1, OA, 1);                                           \
    BARR(); LGKM0(); SCHEDB();                                        \
    __builtin_amdgcn_s_setprio(1); MF(0, 1, a0, bb1);                 \
    __builtin_amdgcn_s_setprio(0); BARR();                            \
    RD_A(a1, CA, 1);                                                  \
    BARR(); LGKM0(); SCHEDB();                                        \
    __builtin_amdgcn_s_setprio(1); MF(1, 0, a1, bb0);                 \
    __builtin_amdgcn_s_setprio(0); BARR();                            \
    VMCNT0(); BARR();                                                 \
    __builtin_amdgcn_s_setprio(1); MF(1, 1, a1, bb1);                 \
    __builtin_amdgcn_s_setprio(0); BARR();                            \
  } while (0)

#define TILE_T2(CA, CB)                                               \
  do {                                                                \
    RD_A(a0, CA, 0); RD_B(bb0, CB, 0);                                \
    RD_B(bb1, CB, 1); RD_A(a1, CA, 1);                                \
    LGKM0(); SCHEDB();                                                \
    MF(0, 0, a0, bb0); MF(0, 1, a0, bb1);                             \
    MF(1, 0, a1, bb0); MF(1, 1, a1, bb1);                             \
  } while (0)

  STAGE(As0, 0, A0buf, 0);
  STAGE(Bs0, 0, B0buf, 0);
  STAGE(As1, 0, A0buf, 1);
  STAGE(Bs1, 0, B0buf, 1);
  STAGE(Bs0, 128, B1buf, 0);
  STAGE(As0, 128, A1buf, 0);
  VMCNT4();
  BARR();

#pragma unroll 1
  for (int t = 0; t + 3 < KT; t += 2) {
    TILE(A0buf, B0buf, A1buf, B1buf, t);
    TILE(A1buf, B1buf, A0buf, B0buf, t + 1);
  }
  TILE_T1(A0buf, B0buf, A1buf, B1buf, KT - 2);
  TILE_T2(A1buf, B1buf);

  BARR();
  {
    float* eb = (float*)(smem + wid * 16384);
    const int gc0 = n0 + wc * 64;
    const f32x4 bv4 = *(const f32x4*)&bias[gc0 + l15 * 4];
#pragma unroll
    for (int mh = 0; mh < 2; mh++) {
#pragma unroll
      for (int mi = 0; mi < 4; mi++) {
#pragma unroll
        for (int nh = 0; nh < 2; nh++)
#pragma unroll
          for (int ni = 0; ni < 2; ni++)
#pragma unroll
            for (int j = 0; j < 4; j++)
              eb[(l4 * 4 + j) * 68 + nh * 32 + ni * 16 + l15] = acc[mh][nh][mi][ni][j];
        int gr0 = m0 + wr * 128 + mh * 64 + mi * 16;
#pragma unroll
        for (int k = 0; k < 4; k++) {
          int r = k * 4 + l4;
          f32x4 v = *(const f32x4*)&eb[r * 68 + l15 * 4];
          v += bv4;
          size_t base = (size_t)(gr0 + r) * N + gc0 + l15 * 4;
          if (EPI == 1) {
#pragma unroll
            for (int q = 0; q < 4; q++)
              v[q] = 0.5f * v[q] * (1.0f + erff(v[q] * 0.70710678118f));
          }
          if (EPI == 2) {
            f32x4 rv = *(const f32x4*)&resid[base];
            *(f32x4*)((float*)outv + base) = v + rv;
          } else {
            ushort4 o4;
            o4.x = f2bf(v[0]); o4.y = f2bf(v[1]); o4.z = f2bf(v[2]); o4.w = f2bf(v[3]);
            *(ushort4*)((unsigned short*)outv + base) = o4;
          }
        }
      }
    }
  }
#undef TILE_T2
#undef TILE_T1
#undef TILE
#undef MF
#undef RD_B
#undef RD_A
#undef STAGE
}

// ---------------- gemmS_k: 256x256 single-buffered, 64KB LDS -> 2 blocks/CU.
// m97-style 2-barrier loop; compiler-visible ds_reads (compiler inserts
// fine-grained lgkmcnt). Cross-block overlap supplies the latency hiding.
template <int EPI>
__global__ __launch_bounds__(512, 4) void gemmS_k(
    const unsigned short* __restrict__ A, const unsigned short* __restrict__ Bt,
    const float* __restrict__ bias, const float* __restrict__ resid,
    void* __restrict__ outv, int N, int K) {
  extern __shared__ __align__(16) char smem[];
  char* Abuf = smem;          // [256][64] swizzled, halves at 0 / 16KB
  char* Bbuf = smem + 32768;

  const int tid = threadIdx.x, lane = tid & 63, wid = tid >> 6;
  const int wr = wid >> 2, wc = wid & 3;
  const int l15 = lane & 15, l4 = lane >> 4;
  const int m0 = blockIdx.x * 256, n0 = blockIdx.y * 256;
  const int KT = K >> 6;
  const size_t K2 = (size_t)K * 2;

  const int toff = (tid >> 3) * (int)K2 + ((((tid & 7) ^ ((tid >> 3) & 7)) << 4));
  const char* As0 = (const char*)A + (size_t)m0 * K2 + toff;
  const char* As1 = As0 + 128 * K2;
  const char* Bs0 = (const char*)Bt + (size_t)n0 * K2 + toff;
  const char* Bs1 = Bs0 + 128 * K2;
  const size_t l64 = 64 * K2;
  const int dst = tid * 16;

  const int s0 = ((l4 ^ (l15 & 7)) << 4);
  const int rbA = (wr * 128 + l15) * 128;
  const int rbB = (wc * 64 + l15) * 128;

  f32x4 acc[2][2][4][2] = {};
  bf16x8 a0[4][2], a1[4][2], bb0[2][2], bb1[2][2];

#define SSTAGE(srcH, ktb, ldsT, half)                       \
  do {                                                      \
    const char* _g = (srcH) + (size_t)(ktb);                \
    glds16(_g, (ldsT) + (half) * 16384 + dst);              \
    glds16(_g + l64, (ldsT) + (half) * 16384 + 8192 + dst); \
  } while (0)

#define SRD_A(dA, CA, mh)                                                          \
  _Pragma("unroll") for (int mi = 0; mi < 4; ++mi)                                 \
  _Pragma("unroll") for (int ks = 0; ks < 2; ++ks)                                 \
    dA[mi][ks] = *(const bf16x8*)((CA) + rbA + (mh) * 8192 + mi * 2048 + (s0 ^ (ks << 6)));

#define SRD_B(dB, CB, nh)                                                          \
  _Pragma("unroll") for (int ni = 0; ni < 2; ++ni)                                 \
  _Pragma("unroll") for (int ks = 0; ks < 2; ++ks)                                 \
    dB[ni][ks] = *(const bf16x8*)((CB) + rbB + (nh) * 4096 + ni * 2048 + (s0 ^ (ks << 6)));

#define SMF(mh, nh, av, bv)                                                        \
  _Pragma("unroll") for (int mi = 0; mi < 4; ++mi)                                 \
  _Pragma("unroll") for (int ni = 0; ni < 2; ++ni)                                 \
  _Pragma("unroll") for (int ks = 0; ks < 2; ++ks)                                 \
    acc[mh][nh][mi][ni] = __builtin_amdgcn_mfma_f32_16x16x32_bf16(                 \
        av[mi][ks], bv[ni][ks], acc[mh][nh][mi][ni], 0, 0, 0);

#pragma unroll 1
  for (int t = 0; t < KT; ++t) {
    const size_t kt = (size_t)t * 128;
    SSTAGE(As0, kt, Abuf, 0);
    SSTAGE(As1, kt, Abuf, 1);
    SSTAGE(Bs0, kt, Bbuf, 0);
    SSTAGE(Bs1, kt, Bbuf, 1);
    VMCNT0();
    BARR();
    SRD_A(a0, Abuf, 0); SRD_A(a1, Abuf, 1);
    SRD_B(bb0, Bbuf, 0); SRD_B(bb1, Bbuf, 1);
    __builtin_amdgcn_s_setprio(1);
    SMF(0, 0, a0, bb0); SMF(0, 1, a0, bb1);
    SMF(1, 0, a1, bb0); SMF(1, 1, a1, bb1);
    __builtin_amdgcn_s_setprio(0);
    __syncthreads();  // all reads done before next stage overwrites
  }

  // coalesced epilogue via per-wave 8KB LDS scratch
  {
    float* eb = (float*)(smem + wid * 8192);
    const int gc0 = n0 + wc * 64;
    const f32x4 bv4 = *(const f32x4*)&bias[gc0 + l15 * 4];
#pragma unroll
    for (int mh = 0; mh < 2; mh++) {
#pragma unroll
      for (int mi = 0; mi < 4; mi++) {
#pragma unroll
        for (int nh = 0; nh < 2; nh++)
#pragma unroll
          for (int ni = 0; ni < 2; ni++)
#pragma unroll
            for (int j = 0; j < 4; j++)
              eb[(l4 * 4 + j) * 68 + nh * 32 + ni * 16 + l15] = acc[mh][nh][mi][ni][j];
        int gr0 = m0 + wr * 128 + mh * 64 + mi * 16;
#pragma unroll
        for (int k = 0; k < 4; k++) {
          int r = k * 4 + l4;
          f32x4 v = *(const f32x4*)&eb[r * 68 + l15 * 4];
          v += bv4;
          size_t base = (size_t)(gr0 + r) * N + gc0 + l15 * 4;
          if (EPI == 1) {
#pragma unroll
            for (int q = 0; q < 4; q++)
              v[q] = 0.5f * v[q] * (1.0f + erff(v[q] * 0.70710678118f));
          }
          if (EPI == 2) {
            f32x4 rv = *(const f32x4*)&resid[base];
            *(f32x4*)((float*)outv + base) = v + rv;
          } else {
            ushort4 o4;
            o4.x = f2bf(v[0]); o4.y = f2bf(v[1]); o4.z = f2bf(v[2]); o4.w = f2bf(v[3]);
            *(ushort4*)((unsigned short*)outv + base) = o4;
          }
        }
      }
    }
  }
#undef SMF
#undef SRD_B
#undef SRD_A
#undef SSTAGE
}

// ---------------- gather K: Kg[bh][p][d] (bf16) from qkv + cache_k
__global__ void gatherk_k(const unsigned short* __restrict__ qkv,
                          const float* __restrict__ cache_k,
                          unsigned short* __restrict__ Kg) {
  int bh = blockIdx.y, b = bh >> 4, h = bh & 15;
  int p = blockIdx.x * 4 + (threadIdx.x >> 6);
  int d = threadIdx.x & 63;
  unsigned short val;
  if (p < 64)
    val = qkv[((size_t)(b * Nn_ + p)) * 3072 + 1024 + h * 64 + d];
  else if (p < 320)
    val = f2bf(cache_k[(((size_t)b * Hh + h) * 1024 + p) * 64 + d]);
  else
    val = qkv[((size_t)(b * Nn_ + p - 256)) * 3072 + 1024 + h * 64 + d];
  Kg[(((size_t)bh) * AVAIL + p) * 64 + d] = val;
}

// ---------------- gather V transposed: Vt[bh][d][p] (bf16)
__global__ void gathervt_k(const unsigned short* __restrict__ qkv,
                           const float* __restrict__ cache_v,
                           unsigned short* __restrict__ Vt) {
  __shared__ float tile[32][33];
  int bh = blockIdx.z, b = bh >> 4, h = bh & 15;
  int p0 = blockIdx.x * 32, d0 = blockIdx.y * 32;
  int tx = threadIdx.x, ty = threadIdx.y;  // 32 x 8
#pragma unroll
  for (int i = 0; i < 4; i++) {
    int p = p0 + ty + i * 8, d = d0 + tx;
    float v;
    if (p < 64)
      v = __uint_as_float((unsigned)qkv[((size_t)(b * Nn_ + p)) * 3072 + 2048 + h * 64 + d] << 16);
    else if (p < 320)
      v = cache_v[(((size_t)b * Hh + h) * 1024 + p) * 64 + d];
    else
      v = __uint_as_float((unsigned)qkv[((size_t)(b * Nn_ + p - 256)) * 3072 + 2048 + h * 64 + d] << 16);
    tile[ty + i * 8][tx] = v;
  }
  __syncthreads();
#pragma unroll
  for (int i = 0; i < 4; i++)
    Vt[(((size_t)bh) * 64 + d0 + ty + i * 8) * AVAIL + p0 + tx] = f2bf(tile[tx][ty + i * 8]);
}

// ---------------- flash attention (double-buffered K/V chunks)
__global__ __launch_bounds__(256) void attn_k(
    const unsigned short* __restrict__ qkv, const unsigned short* __restrict__ Kg,
    const unsigned short* __restrict__ Vt, unsigned short* __restrict__ o) {
  __shared__ __attribute__((aligned(16))) unsigned short Qs[64 * 64];
  __shared__ __attribute__((aligned(16))) unsigned short Ks[2][64 * 64];
  __shared__ __attribute__((aligned(16))) unsigned short Vs[2][64 * 64];
  __shared__ __attribute__((aligned(16))) unsigned short Ps[4][16 * 64];

  const int tid = threadIdx.x;
  const int lane = tid & 63;
  const int w = tid >> 6;
  const int qt = blockIdx.x;
  const int bh = blockIdx.y, b = bh >> 4, h = bh & 15;
  const float scale = 0.125f;

  const char* kbase = (const char*)(Kg + (size_t)bh * AVAIL * 64);
  const char* vbase = (const char*)(Vt + (size_t)bh * 64 * AVAIL);
  const int vr = tid >> 3;
  const int vcb = (tid & 7) << 4;

#define STAGE_KV(c, buf)                                                          \
  do {                                                                            \
    glds16(kbase + (size_t)(c) * 8192 + tid * 16, (char*)Ks[buf] + tid * 16);     \
    glds16(kbase + (size_t)(c) * 8192 + 4096 + tid * 16,                          \
           (char*)Ks[buf] + 4096 + tid * 16);                                     \
    glds16(vbase + (size_t)vr * (AVAIL * 2) + (c) * 128 + vcb,                    \
           (char*)Vs[buf] + tid * 16);                                            \
    glds16(vbase + (size_t)(vr + 32) * (AVAIL * 2) + (c) * 128 + vcb,             \
           (char*)Vs[buf] + 4096 + tid * 16);                                     \
  } while (0)

  {
    const char* qb = (const char*)qkv;
    glds16(qb + ((size_t)(b * Nn_ + qt * 64 + vr) * 3072 + h * 64) * 2 + vcb,
           (char*)Qs + tid * 16);
    glds16(qb + ((size_t)(b * Nn_ + qt * 64 + 32 + vr) * 3072 + h * 64) * 2 + vcb,
           (char*)Qs + 4096 + tid * 16);
  }
  STAGE_KV(0, 0);
  asm volatile("s_waitcnt vmcnt(0)" ::: "memory");
  __syncthreads();

  bf16x8 qf[2];
#pragma unroll
  for (int t = 0; t < 2; t++)
    qf[t] = *(const bf16x8*)&Qs[(w * 16 + (lane & 15)) * 64 + t * 32 + (lane >> 4) * 8];

  float m_run[4], l_run[4];
  f32x4 oacc[4] = {};
#pragma unroll
  for (int j = 0; j < 4; j++) { m_run[j] = -1e30f; l_run[j] = 0.f; }

  for (int c = 0; c < 13; c++) {
    const int cur = c & 1;
    if (c < 12) STAGE_KV(c + 1, cur ^ 1);

    f32x4 s[4] = {};
#pragma unroll
    for (int nt = 0; nt < 4; nt++) {
#pragma unroll
      for (int t = 0; t < 2; t++) {
        bf16x8 kf =
            *(const bf16x8*)&Ks[cur][(nt * 16 + (lane & 15)) * 64 + t * 32 + (lane >> 4) * 8];
        s[nt] = __builtin_amdgcn_mfma_f32_16x16x32_bf16(qf[t], kf, s[nt], 0, 0, 0);
      }
    }

    float p[4][4];
#pragma unroll
    for (int j = 0; j < 4; j++) {
      float mx = fmaxf(fmaxf(s[0][j], s[1][j]), fmaxf(s[2][j], s[3][j])) * scale;
#pragma unroll
      for (int off = 1; off < 16; off <<= 1) mx = fmaxf(mx, __shfl_xor(mx, off));
      float m_new = fmaxf(m_run[j], mx);
      float alpha = __expf(m_run[j] - m_new);
      float sum = 0.f;
#pragma unroll
      for (int nt = 0; nt < 4; nt++) {
        p[nt][j] = __expf(s[nt][j] * scale - m_new);
        sum += p[nt][j];
      }
#pragma unroll
      for (int off = 1; off < 16; off <<= 1) sum += __shfl_xor(sum, off);
      l_run[j] = l_run[j] * alpha + sum;
      m_run[j] = m_new;
#pragma unroll
      for (int nt2 = 0; nt2 < 4; nt2++) oacc[nt2][j] *= alpha;
    }

#pragma unroll
    for (int nt = 0; nt < 4; nt++)
#pragma unroll
      for (int j = 0; j < 4; j++)
        Ps[w][((lane >> 4) * 4 + j) * 64 + nt * 16 + (lane & 15)] = f2bf(p[nt][j]);

    bf16x8 pa[2];
#pragma unroll
    for (int t = 0; t < 2; t++)
      pa[t] = *(const bf16x8*)&Ps[w][(lane & 15) * 64 + t * 32 + (lane >> 4) * 8];
#pragma unroll
    for (int nt2 = 0; nt2 < 4; nt2++) {
#pragma unroll
      for (int t = 0; t < 2; t++) {
        bf16x8 vf =
            *(const bf16x8*)&Vs[cur][(nt2 * 16 + (lane & 15)) * 64 + t * 32 + (lane >> 4) * 8];
        oacc[nt2] = __builtin_amdgcn_mfma_f32_16x16x32_bf16(pa[t], vf, oacc[nt2], 0, 0, 0);
      }
    }
    __syncthreads();
  }

#pragma unroll
  for (int nt2 = 0; nt2 < 4; nt2++) {
#pragma unroll
    for (int j = 0; j < 4; j++) {
      int q = qt * 64 + w * 16 + (lane >> 4) * 4 + j;
      float v = oacc[nt2][j] / l_run[j];
      o[((size_t)(b * Nn_ + q)) * Cc + h * 64 + nt2 * 16 + (lane & 15)] = f2bf(v);
    }
  }
#undef STAGE_KV
}

extern "C" void kernel_launch(void* const* d_in, const int* in_sizes, int n_in,
                              void* d_out, int out_size, void* d_ws, size_t ws_size,
                              hipStream_t stream) {
  const float* x = (const float*)d_in[0];
  const float* cache_k = (const float*)d_in[1];
  const float* cache_v = (const float*)d_in[2];
  const float* qkv_w = (const float*)d_in[3];
  const float* qkv_b = (const float*)d_in[4];
  const float* proj_w = (const float*)d_in[5];
  const float* proj_b = (const float*)d_in[6];
  const float* n1w = (const float*)d_in[7];
  const float* n1b = (const float*)d_in[8];
  const float* n2w = (const float*)d_in[9];
  const float* n2b = (const float*)d_in[10];
  const float* fc1w = (const float*)d_in[11];
  const float* fc1b = (const float*)d_in[12];
  const float* fc2w = (const float*)d_in[13];
  const float* fc2b = (const float*)d_in[14];

  char* ws = (char*)d_ws;
  unsigned short* wq_t = (unsigned short*)(ws + 0);          //  [3072][1024]
  unsigned short* wp_t = (unsigned short*)(ws + 6291456);    //  [1024][1024]
  unsigned short* w1_t = (unsigned short*)(ws + 8388608);    //  [4096][1024]
  unsigned short* w2_t = (unsigned short*)(ws + 16777216);   //  [1024][4096]
  float* x2           = (float*)(ws + 25165824);             //  [9216][1024] f32
  unsigned short* obuf = (unsigned short*)(ws + 62914560);   //  [9216][1024]
  unsigned short* hbuf = (unsigned short*)(ws + 81788928);   //  [9216][1024]
  unsigned short* vt   = (unsigned short*)(ws + 100663296);  //  [256][64][832]
  unsigned short* qkvb = (unsigned short*)(ws + 127926272);  //  [9216][3072]
  unsigned short* kg   = (unsigned short*)(ws + 184549376);  //  [256][832][64]
  unsigned short* midb = qkvb;  // fc1 out [9216][4096]; overruns into kg (dead by then)

  hipFuncSetAttribute((const void*)&gemm8_k<0>, hipFuncAttributeMaxDynamicSharedMemorySize, 131072);
  hipFuncSetAttribute((const void*)&gemm8_k<2>, hipFuncAttributeMaxDynamicSharedMemorySize, 131072);
  hipFuncSetAttribute((const void*)&gemmS_k<1>, hipFuncAttributeMaxDynamicSharedMemorySize, 65536);
  hipFuncSetAttribute((const void*)&gemmS_k<2>, hipFuncAttributeMaxDynamicSharedMemorySize, 65536);

  dim3 b328(32, 8);
  wtrans_k<<<dim3(32, 96), b328, 0, stream>>>(qkv_w, wq_t, 1024, 3072);
  wtrans_k<<<dim3(32, 32), b328, 0, stream>>>(proj_w, wp_t, 1024, 1024);
  wtrans_k<<<dim3(32, 128), b328, 0, stream>>>(fc1w, w1_t, 1024, 4096);
  wtrans_k<<<dim3(128, 32), b328, 0, stream>>>(fc2w, w2_t, 4096, 1024);

  ln_k<<<ROWS, 256, 0, stream>>>(x, n1w, n1b, hbuf);
  gemm8_k<0><<<dim3(36, 12), 512, 131072, stream>>>(hbuf, wq_t, qkv_b, nullptr, qkvb, 3072, 1024);

  gatherk_k<<<dim3(208, 256), 256, 0, stream>>>(qkvb, cache_k, kg);
  gathervt_k<<<dim3(26, 2, 256), b328, 0, stream>>>(qkvb, cache_v, vt);
  attn_k<<<dim3(9, 256), 256, 0, stream>>>(qkvb, kg, vt, obuf);

  gemm8_k<2><<<dim3(36, 4), 512, 131072, stream>>>(obuf, wp_t, proj_b, x, x2, 1024, 1024);
  ln_k<<<ROWS, 256, 0, stream>>>(x2, n2w, n2b, hbuf);

  // A/B experiment: FC1 + FC2 on single-buffered 2-blocks/CU variant
  gemmS_k<1><<<dim3(36, 16), 512, 65536, stream>>>(hbuf, w1_t, fc1b, nullptr, midb, 4096, 1024);
  gemmS_k<2><<<dim3(36, 4), 512, 65536, stream>>>(midb, w2_t, fc2b, x2, (float*)d_out, 1024, 4096);
}

// Round 12
// 562.119 us; speedup vs baseline: 5.8712x; 5.8712x over previous
//
#include <hip/hip_runtime.h>

// Problem constants
#define Bb 16
#define Nn_ 576
#define Cc 1024
#define Hh 16
#define HD 64
#define HID 4096
#define AVAIL 832   // CUR(256) + N(576)
#define ROWS (Bb*Nn_)  // 9216

typedef __bf16 bf16x8 __attribute__((ext_vector_type(8)));
typedef float f32x4 __attribute__((ext_vector_type(4)));

__device__ __forceinline__ unsigned short f2bf(float f) {
  unsigned u = __float_as_uint(f);
  u += 0x7FFF + ((u >> 16) & 1);
  return (unsigned short)(u >> 16);
}

__device__ __forceinline__ void glds16(const void* g, void* l) {
  __builtin_amdgcn_global_load_lds(
      (const __attribute__((address_space(1))) void*)g,
      (__attribute__((address_space(3))) void*)l, 16, 0, 0);
}

__device__ __forceinline__ bf16x8 ds_read128(const void* p) {
  bf16x8 r;
  asm volatile("ds_read_b128 %0, %1"
               : "=v"(r)
               : "v"((const __attribute__((address_space(3))) char*)p));
  return r;
}

#define BARR() asm volatile("s_barrier" ::: "memory")
#define VMCNT8() asm volatile("s_waitcnt vmcnt(8)" ::: "memory")
#define VMCNT4() asm volatile("s_waitcnt vmcnt(4)" ::: "memory")
#define VMCNT0() asm volatile("s_waitcnt vmcnt(0)" ::: "memory")
#define LGKM0() asm volatile("s_waitcnt lgkmcnt(0)" ::: "memory")
#define SCHEDB() __builtin_amdgcn_sched_barrier(0)

// ---------------- weight convert+transpose: in [K][N] f32 -> out [N][K] bf16
// 64x64 tiles, 16B stores (full-line writes; avoids write-allocate overfetch)
__global__ void wtrans2_k(const float* __restrict__ in, unsigned short* __restrict__ out,
                          int K, int N) {
  __shared__ float tile[64][65];
  int k0 = blockIdx.x * 64, n0 = blockIdx.y * 64;
  int tid = threadIdx.x;  // 256
  int nl = tid & 63, kl0 = tid >> 6;
#pragma unroll
  for (int j = 0; j < 16; j++) {
    int kl = kl0 + j * 4;
    tile[nl][kl] = in[(size_t)(k0 + kl) * N + n0 + nl];
  }
  __syncthreads();
  int no0 = tid >> 3, ko = (tid & 7) * 8;
#pragma unroll
  for (int i = 0; i < 2; i++) {
    int no = no0 + i * 32;
    const float* tp = &tile[no][ko];
    ushort4 oa, ob;
    oa.x = f2bf(tp[0]); oa.y = f2bf(tp[1]); oa.z = f2bf(tp[2]); oa.w = f2bf(tp[3]);
    ob.x = f2bf(tp[4]); ob.y = f2bf(tp[5]); ob.z = f2bf(tp[6]); ob.w = f2bf(tp[7]);
    unsigned short* op = &out[(size_t)(n0 + no) * K + k0 + ko];
    *(ushort4*)op = oa;
    *(ushort4*)(op + 4) = ob;
  }
}

// ---------------- LayerNorm f32 -> bf16, one block per row of 1024
__global__ void ln_k(const float* __restrict__ x, const float* __restrict__ w,
                     const float* __restrict__ bi, unsigned short* __restrict__ out) {
  int row = blockIdx.x;
  int t = threadIdx.x;
  float4 v = ((const float4*)(x + (size_t)row * Cc))[t];
  float s = v.x + v.y + v.z + v.w;
  float s2 = v.x * v.x + v.y * v.y + v.z * v.z + v.w * v.w;
#pragma unroll
  for (int off = 1; off < 64; off <<= 1) { s += __shfl_xor(s, off); s2 += __shfl_xor(s2, off); }
  __shared__ float red[8];
  int wid = t >> 6, lane = t & 63;
  if (lane == 0) { red[wid] = s; red[4 + wid] = s2; }
  __syncthreads();
  s = red[0] + red[1] + red[2] + red[3];
  s2 = red[4] + red[5] + red[6] + red[7];
  float mean = s * (1.0f / Cc);
  float var = s2 * (1.0f / Cc) - mean * mean;
  float rstd = rsqrtf(var + 1e-5f);
  float4 wv = ((const float4*)w)[t];
  float4 bv = ((const float4*)bi)[t];
  ushort4 ov;
  ov.x = f2bf((v.x - mean) * rstd * wv.x + bv.x);
  ov.y = f2bf((v.y - mean) * rstd * wv.y + bv.y);
  ov.z = f2bf((v.z - mean) * rstd * wv.z + bv.z);
  ov.w = f2bf((v.w - mean) * rstd * wv.w + bv.w);
  *(ushort4*)(out + (size_t)row * Cc + t * 4) = ov;
}

// ---------------- 256x256 8-wave pipelined GEMM (R6 structure), 128KB LDS dbuf.
template <int EPI>
__global__ __launch_bounds__(512, 2) void gemm8_k(
    const unsigned short* __restrict__ A, const unsigned short* __restrict__ Bt,
    const float* __restrict__ bias, const float* __restrict__ resid,
    void* __restrict__ outv, int N, int K) {
  extern __shared__ __align__(16) char smem[];
  char* A0buf = smem;
  char* B0buf = smem + 32768;
  char* A1buf = smem + 65536;
  char* B1buf = smem + 98304;

  const int tid = threadIdx.x, lane = tid & 63, wid = tid >> 6;
  const int wr = wid >> 2, wc = wid & 3;
  const int l15 = lane & 15, l4 = lane >> 4;
  const int m0 = blockIdx.x * 256, n0 = blockIdx.y * 256;
  const int KT = K >> 6;
  const size_t K2 = (size_t)K * 2;

  const int toff = (tid >> 3) * (int)K2 + ((((tid & 7) ^ ((tid >> 3) & 7)) << 4));
  const char* As0 = (const char*)A + (size_t)m0 * K2 + toff;
  const char* As1 = As0 + 128 * K2;
  const char* Bs0 = (const char*)Bt + (size_t)n0 * K2 + toff;
  const char* Bs1 = Bs0 + 128 * K2;
  const size_t l64 = 64 * K2;
  const int dst = tid * 16;

  const int s0 = ((l4 ^ (l15 & 7)) << 4);
  const int rbA = (wr * 128 + l15) * 128;
  const int rbB = (wc * 64 + l15) * 128;

  f32x4 acc[2][2][4][2] = {};
  bf16x8 a0[4][2], a1[4][2], bb0[2][2], bb1[2][2];

#define STAGE(srcH, ktb, ldsT, half)                        \
  do {                                                      \
    const char* _g = (srcH) + (size_t)(ktb);                \
    glds16(_g, (ldsT) + (half) * 16384 + dst);              \
    glds16(_g + l64, (ldsT) + (half) * 16384 + 8192 + dst); \
  } while (0)

#define RD_A(dA, CA, mh)                                                           \
  _Pragma("unroll") for (int mi = 0; mi < 4; ++mi)                                 \
  _Pragma("unroll") for (int ks = 0; ks < 2; ++ks)                                 \
    dA[mi][ks] = ds_read128((CA) + rbA + (mh) * 8192 + mi * 2048 + (s0 ^ (ks << 6)));

#define RD_B(dB, CB, nh)                                                           \
  _Pragma("unroll") for (int ni = 0; ni < 2; ++ni)                                 \
  _Pragma("unroll") for (int ks = 0; ks < 2; ++ks)                                 \
    dB[ni][ks] = ds_read128((CB) + rbB + (nh) * 4096 + ni * 2048 + (s0 ^ (ks << 6)));

#define MF(mh, nh, av, bv)                                                         \
  _Pragma("unroll") for (int mi = 0; mi < 4; ++mi)                                 \
  _Pragma("unroll") for (int ni = 0; ni < 2; ++ni)                                 \
  _Pragma("unroll") for (int ks = 0; ks < 2; ++ks)                                 \
    acc[mh][nh][mi][ni] = __builtin_amdgcn_mfma_f32_16x16x32_bf16(                 \
        av[mi][ks], bv[ni][ks], acc[mh][nh][mi][ni], 0, 0, 0);

#define TILE(CA, CB, OA, OB, t)                                       \
  do {                                                                \
    const size_t kt1 = (size_t)((t) + 1) * 128;                       \
    const size_t kt2 = (size_t)((t) + 2) * 128;                       \
    RD_A(a0, CA, 0); RD_B(bb0, CB, 0);                                \
    STAGE(Bs1, kt1, OB, 1);                                           \
    BARR(); LGKM0(); SCHEDB();                                        \
    __builtin_amdgcn_s_setprio(1); MF(0, 0, a0, bb0);                 \
    __builtin_amdgcn_s_setprio(0); BARR();                            \
    RD_B(bb1, CB, 1);                                                 \
    STAGE(As1, kt1, OA, 1);                                           \
    BARR(); LGKM0(); SCHEDB();                                        \
    __builtin_amdgcn_s_setprio(1); MF(0, 1, a0, bb1);                 \
    __builtin_amdgcn_s_setprio(0); BARR();                            \
    RD_A(a1, CA, 1);                                                  \
    STAGE(Bs0, kt2, CB, 0);                                           \
    BARR(); LGKM0(); SCHEDB();                                        \
    __builtin_amdgcn_s_setprio(1); MF(1, 0, a1, bb0);                 \
    __builtin_amdgcn_s_setprio(0); BARR();                            \
    STAGE(As0, kt2, CA, 0);                                           \
    VMCNT4(); BARR();                                                 \
    __builtin_amdgcn_s_setprio(1); MF(1, 1, a1, bb1);                 \
    __builtin_amdgcn_s_setprio(0); BARR();                            \
  } while (0)

#define TILE_T1(CA, CB, OA, OB, t)                                    \
  do {                                                                \
    const size_t kt1 = (size_t)((t) + 1) * 128;                       \
    RD_A(a0, CA, 0); RD_B(bb0, CB, 0);                                \
    STAGE(Bs1, kt1, OB, 1);                                           \
    BARR(); LGKM0(); SCHEDB();                                        \
    __builtin_amdgcn_s_setprio(1); MF(0, 0, a0, bb0);                 \
    __builtin_amdgcn_s_setprio(0); BARR();                            \
    RD_B(bb1, CB, 1);                                                 \
    STAGE(As1, kt1, OA, 1);                                           \
    BARR(); LGKM0(); SCHEDB();                                        \
    __builtin_amdgcn_s_setprio(1); MF(0, 1, a0, bb1);                 \
    __builtin_amdgcn_s_setprio(0); BARR();                            \
    RD_A(a1, CA, 1);                                                  \
    BARR(); LGKM0(); SCHEDB();                                        \
    __builtin_amdgcn_s_setprio(1); MF(1, 0, a1, bb0);                 \
    __builtin_amdgcn_s_setprio(0); BARR();                            \
    VMCNT0(); BARR();                                                 \
    __builtin_amdgcn_s_setprio(1); MF(1, 1, a1, bb1);                 \
    __builtin_amdgcn_s_setprio(0); BARR();                            \
  } while (0)

#define TILE_T2(CA, CB)                                               \
  do {                                                                \
    RD_A(a0, CA, 0); RD_B(bb0, CB, 0);                                \
    RD_B(bb1, CB, 1); RD_A(a1, CA, 1);                                \
    LGKM0(); SCHEDB();                                                \
    MF(0, 0, a0, bb0); MF(0, 1, a0, bb1);                             \
    MF(1, 0, a1, bb0); MF(1, 1, a1, bb1);                             \
  } while (0)

  STAGE(As0, 0, A0buf, 0);
  STAGE(Bs0, 0, B0buf, 0);
  STAGE(As1, 0, A0buf, 1);
  STAGE(Bs1, 0, B0buf, 1);
  STAGE(Bs0, 128, B1buf, 0);
  STAGE(As0, 128, A1buf, 0);
  VMCNT4();
  BARR();

#pragma unroll 1
  for (int t = 0; t + 3 < KT; t += 2) {
    TILE(A0buf, B0buf, A1buf, B1buf, t);
    TILE(A1buf, B1buf, A0buf, B0buf, t + 1);
  }
  TILE_T1(A0buf, B0buf, A1buf, B1buf, KT - 2);
  TILE_T2(A1buf, B1buf);

  BARR();
  {
    float* eb = (float*)(smem + wid * 16384);
    const int gc0 = n0 + wc * 64;
    const f32x4 bv4 = *(const f32x4*)&bias[gc0 + l15 * 4];
#pragma unroll
    for (int mh = 0; mh < 2; mh++) {
#pragma unroll
      for (int mi = 0; mi < 4; mi++) {
#pragma unroll
        for (int nh = 0; nh < 2; nh++)
#pragma unroll
          for (int ni = 0; ni < 2; ni++)
#pragma unroll
            for (int j = 0; j < 4; j++)
              eb[(l4 * 4 + j) * 68 + nh * 32 + ni * 16 + l15] = acc[mh][nh][mi][ni][j];
        int gr0 = m0 + wr * 128 + mh * 64 + mi * 16;
#pragma unroll
        for (int k = 0; k < 4; k++) {
          int r = k * 4 + l4;
          f32x4 v = *(const f32x4*)&eb[r * 68 + l15 * 4];
          v += bv4;
          size_t base = (size_t)(gr0 + r) * N + gc0 + l15 * 4;
          if (EPI == 1) {
#pragma unroll
            for (int q = 0; q < 4; q++)
              v[q] = 0.5f * v[q] * (1.0f + erff(v[q] * 0.70710678118f));
          }
          if (EPI == 2) {
            f32x4 rv = *(const f32x4*)&resid[base];
            *(f32x4*)((float*)outv + base) = v + rv;
          } else {
            ushort4 o4;
            o4.x = f2bf(v[0]); o4.y = f2bf(v[1]); o4.z = f2bf(v[2]); o4.w = f2bf(v[3]);
            *(ushort4*)((unsigned short*)outv + base) = o4;
          }
        }
      }
    }
  }
#undef TILE_T2
#undef TILE_T1
#undef TILE
#undef MF
#undef RD_B
#undef RD_A
#undef STAGE
}

// ---------------- gemmD_k: 128x128 tile, 4 waves, BK=64, double-buffered
// 64KB LDS -> 2 blocks/CU co-resident + counted vmcnt(8) pipeline.
// ~160 regs/wave (<= 256 budget at launch_bounds(256,2)): no spill.
template <int EPI>
__global__ __launch_bounds__(256, 2) void gemmD_k(
    const unsigned short* __restrict__ A, const unsigned short* __restrict__ Bt,
    const float* __restrict__ bias, const float* __restrict__ resid,
    void* __restrict__ outv, int N, int K) {
  extern __shared__ __align__(16) char smem[];
  char* A0buf = smem;            // 16KB each
  char* B0buf = smem + 16384;
  char* A1buf = smem + 32768;
  char* B1buf = smem + 49152;

  const int tid = threadIdx.x, lane = tid & 63, wid = tid >> 6;
  const int wr = wid >> 1, wc = wid & 1;
  const int l15 = lane & 15, l4 = lane >> 4;
  const int m0 = blockIdx.x * 128, n0 = blockIdx.y * 128;
  const int KT = K >> 6;
  const size_t K2 = (size_t)K * 2;

  const int toff = (tid >> 3) * (int)K2 + ((((tid & 7) ^ ((tid >> 3) & 7)) << 4));
  const char* AsD = (const char*)A + (size_t)m0 * K2 + toff;
  const char* BsD = (const char*)Bt + (size_t)n0 * K2 + toff;
  const size_t l32 = 32 * K2;
  const int dst = tid * 16;

  const int s0 = ((l4 ^ (l15 & 7)) << 4);
  const int rbA = (wr * 64 + l15) * 128;
  const int rbB = (wc * 64 + l15) * 128;

  f32x4 acc[4][4] = {};
  bf16x8 av[4][2], bv[4][2];

#define DSTAGE(src, ktb, ldsT)                  \
  do {                                          \
    const char* _g = (src) + (size_t)(ktb);     \
    glds16(_g, (ldsT) + dst);                   \
    glds16(_g + l32, (ldsT) + 4096 + dst);      \
    glds16(_g + 2 * l32, (ldsT) + 8192 + dst);  \
    glds16(_g + 3 * l32, (ldsT) + 12288 + dst); \
  } while (0)

#define DRD(CA, CB)                                                          \
  do {                                                                       \
    _Pragma("unroll") for (int mi = 0; mi < 4; ++mi)                         \
    _Pragma("unroll") for (int ks = 0; ks < 2; ++ks)                         \
      av[mi][ks] = ds_read128((CA) + rbA + mi * 2048 + (s0 ^ (ks << 6)));    \
    _Pragma("unroll") for (int ni = 0; ni < 4; ++ni)                         \
    _Pragma("unroll") for (int ks = 0; ks < 2; ++ks)                         \
      bv[ni][ks] = ds_read128((CB) + rbB + ni * 2048 + (s0 ^ (ks << 6)));    \
  } while (0)

#define DMF()                                                                \
  _Pragma("unroll") for (int mi = 0; mi < 4; ++mi)                           \
  _Pragma("unroll") for (int ni = 0; ni < 4; ++ni)                           \
  _Pragma("unroll") for (int ks = 0; ks < 2; ++ks)                           \
    acc[mi][ni] = __builtin_amdgcn_mfma_f32_16x16x32_bf16(                   \
        av[mi][ks], bv[ni][ks], acc[mi][ni], 0, 0, 0);

  // prologue: tiles 0 and 1 (8 loads each); drain tile0, keep tile1 flying
  DSTAGE(AsD, 0, A0buf);
  DSTAGE(BsD, 0, B0buf);
  DSTAGE(AsD, 128, A1buf);
  DSTAGE(BsD, 128, B1buf);
  VMCNT8();
  BARR();

#pragma unroll 1
  for (int t = 0; t + 3 < KT; t += 2) {
    // tile t (buf0): read; barrier; stage t+2 into buf0; MFMA; vmcnt(8)=t+1 landed
    DRD(A0buf, B0buf);
    LGKM0(); SCHEDB(); BARR();
    DSTAGE(AsD, (size_t)(t + 2) * 128, A0buf);
    DSTAGE(BsD, (size_t)(t + 2) * 128, B0buf);
    __builtin_amdgcn_s_setprio(1); DMF(); __builtin_amdgcn_s_setprio(0);
    VMCNT8(); BARR();
    // tile t+1 (buf1)
    DRD(A1buf, B1buf);
    LGKM0(); SCHEDB(); BARR();
    DSTAGE(AsD, (size_t)(t + 3) * 128, A1buf);
    DSTAGE(BsD, (size_t)(t + 3) * 128, B1buf);
    __builtin_amdgcn_s_setprio(1); DMF(); __builtin_amdgcn_s_setprio(0);
    VMCNT8(); BARR();
  }
  // tile KT-2 (buf0): no stage; drain tile KT-1's loads
  DRD(A0buf, B0buf);
  LGKM0(); SCHEDB(); BARR();
  __builtin_amdgcn_s_setprio(1); DMF(); __builtin_amdgcn_s_setprio(0);
  VMCNT0(); BARR();
  // tile KT-1 (buf1): pure compute
  DRD(A1buf, B1buf);
  LGKM0(); SCHEDB();
  DMF();

  // coalesced epilogue via per-wave 8KB LDS scratch (buf0 region; buf1 untouched)
  BARR();
  {
    float* eb = (float*)(smem + wid * 8192);
    const int gc0 = n0 + wc * 64;
    const f32x4 bv4 = *(const f32x4*)&bias[gc0 + l15 * 4];
#pragma unroll
    for (int mi = 0; mi < 4; mi++) {
#pragma unroll
      for (int ni = 0; ni < 4; ni++)
#pragma unroll
        for (int j = 0; j < 4; j++)
          eb[(l4 * 4 + j) * 68 + ni * 16 + l15] = acc[mi][ni][j];
      int gr0 = m0 + wr * 64 + mi * 16;
#pragma unroll
      for (int k = 0; k < 4; k++) {
        int r = k * 4 + l4;
        f32x4 v = *(const f32x4*)&eb[r * 68 + l15 * 4];
        v += bv4;
        size_t base = (size_t)(gr0 + r) * N + gc0 + l15 * 4;
        if (EPI == 1) {
#pragma unroll
          for (int q = 0; q < 4; q++)
            v[q] = 0.5f * v[q] * (1.0f + erff(v[q] * 0.70710678118f));
        }
        if (EPI == 2) {
          f32x4 rv = *(const f32x4*)&resid[base];
          *(f32x4*)((float*)outv + base) = v + rv;
        } else {
          ushort4 o4;
          o4.x = f2bf(v[0]); o4.y = f2bf(v[1]); o4.z = f2bf(v[2]); o4.w = f2bf(v[3]);
          *(ushort4*)((unsigned short*)outv + base) = o4;
        }
      }
    }
  }
#undef DMF
#undef DRD
#undef DSTAGE
}

// ---------------- gather K: Kg[bh][p][d] (bf16) from qkv + cache_k
__global__ void gatherk_k(const unsigned short* __restrict__ qkv,
                          const float* __restrict__ cache_k,
                          unsigned short* __restrict__ Kg) {
  int bh = blockIdx.y, b = bh >> 4, h = bh & 15;
  int p = blockIdx.x * 4 + (threadIdx.x >> 6);
  int d = threadIdx.x & 63;
  unsigned short val;
  if (p < 64)
    val = qkv[((size_t)(b * Nn_ + p)) * 3072 + 1024 + h * 64 + d];
  else if (p < 320)
    val = f2bf(cache_k[(((size_t)b * Hh + h) * 1024 + p) * 64 + d]);
  else
    val = qkv[((size_t)(b * Nn_ + p - 256)) * 3072 + 1024 + h * 64 + d];
  Kg[(((size_t)bh) * AVAIL + p) * 64 + d] = val;
}

// ---------------- gather V transposed: Vt[bh][d][p] (bf16)
__global__ void gathervt_k(const unsigned short* __restrict__ qkv,
                           const float* __restrict__ cache_v,
                           unsigned short* __restrict__ Vt) {
  __shared__ float tile[32][33];
  int bh = blockIdx.z, b = bh >> 4, h = bh & 15;
  int p0 = blockIdx.x * 32, d0 = blockIdx.y * 32;
  int tx = threadIdx.x, ty = threadIdx.y;  // 32 x 8
#pragma unroll
  for (int i = 0; i < 4; i++) {
    int p = p0 + ty + i * 8, d = d0 + tx;
    float v;
    if (p < 64)
      v = __uint_as_float((unsigned)qkv[((size_t)(b * Nn_ + p)) * 3072 + 2048 + h * 64 + d] << 16);
    else if (p < 320)
      v = cache_v[(((size_t)b * Hh + h) * 1024 + p) * 64 + d];
    else
      v = __uint_as_float((unsigned)qkv[((size_t)(b * Nn_ + p - 256)) * 3072 + 2048 + h * 64 + d] << 16);
    tile[ty + i * 8][tx] = v;
  }
  __syncthreads();
#pragma unroll
  for (int i = 0; i < 4; i++)
    Vt[(((size_t)bh) * 64 + d0 + ty + i * 8) * AVAIL + p0 + tx] = f2bf(tile[tx][ty + i * 8]);
}

// ---------------- flash attention (double-buffered K/V chunks)
__global__ __launch_bounds__(256) void attn_k(
    const unsigned short* __restrict__ qkv, const unsigned short* __restrict__ Kg,
    const unsigned short* __restrict__ Vt, unsigned short* __restrict__ o) {
  __shared__ __attribute__((aligned(16))) unsigned short Qs[64 * 64];
  __shared__ __attribute__((aligned(16))) unsigned short Ks[2][64 * 64];
  __shared__ __attribute__((aligned(16))) unsigned short Vs[2][64 * 64];
  __shared__ __attribute__((aligned(16))) unsigned short Ps[4][16 * 64];

  const int tid = threadIdx.x;
  const int lane = tid & 63;
  const int w = tid >> 6;
  const int qt = blockIdx.x;
  const int bh = blockIdx.y, b = bh >> 4, h = bh & 15;
  const float scale = 0.125f;

  const char* kbase = (const char*)(Kg + (size_t)bh * AVAIL * 64);
  const char* vbase = (const char*)(Vt + (size_t)bh * 64 * AVAIL);
  const int vr = tid >> 3;
  const int vcb = (tid & 7) << 4;

#define STAGE_KV(c, buf)                                                          \
  do {                                                                            \
    glds16(kbase + (size_t)(c) * 8192 + tid * 16, (char*)Ks[buf] + tid * 16);     \
    glds16(kbase + (size_t)(c) * 8192 + 4096 + tid * 16,                          \
           (char*)Ks[buf] + 4096 + tid * 16);                                     \
    glds16(vbase + (size_t)vr * (AVAIL * 2) + (c) * 128 + vcb,                    \
           (char*)Vs[buf] + tid * 16);                                            \
    glds16(vbase + (size_t)(vr + 32) * (AVAIL * 2) + (c) * 128 + vcb,             \
           (char*)Vs[buf] + 4096 + tid * 16);                                     \
  } while (0)

  {
    const char* qb = (const char*)qkv;
    glds16(qb + ((size_t)(b * Nn_ + qt * 64 + vr) * 3072 + h * 64) * 2 + vcb,
           (char*)Qs + tid * 16);
    glds16(qb + ((size_t)(b * Nn_ + qt * 64 + 32 + vr) * 3072 + h * 64) * 2 + vcb,
           (char*)Qs + 4096 + tid * 16);
  }
  STAGE_KV(0, 0);
  asm volatile("s_waitcnt vmcnt(0)" ::: "memory");
  __syncthreads();

  bf16x8 qf[2];
#pragma unroll
  for (int t = 0; t < 2; t++)
    qf[t] = *(const bf16x8*)&Qs[(w * 16 + (lane & 15)) * 64 + t * 32 + (lane >> 4) * 8];

  float m_run[4], l_run[4];
  f32x4 oacc[4] = {};
#pragma unroll
  for (int j = 0; j < 4; j++) { m_run[j] = -1e30f; l_run[j] = 0.f; }

  for (int c = 0; c < 13; c++) {
    const int cur = c & 1;
    if (c < 12) STAGE_KV(c + 1, cur ^ 1);

    f32x4 s[4] = {};
#pragma unroll
    for (int nt = 0; nt < 4; nt++) {
#pragma unroll
      for (int t = 0; t < 2; t++) {
        bf16x8 kf =
            *(const bf16x8*)&Ks[cur][(nt * 16 + (lane & 15)) * 64 + t * 32 + (lane >> 4) * 8];
        s[nt] = __builtin_amdgcn_mfma_f32_16x16x32_bf16(qf[t], kf, s[nt], 0, 0, 0);
      }
    }

    float p[4][4];
#pragma unroll
    for (int j = 0; j < 4; j++) {
      float mx = fmaxf(fmaxf(s[0][j], s[1][j]), fmaxf(s[2][j], s[3][j])) * scale;
#pragma unroll
      for (int off = 1; off < 16; off <<= 1) mx = fmaxf(mx, __shfl_xor(mx, off));
      float m_new = fmaxf(m_run[j], mx);
      float alpha = __expf(m_run[j] - m_new);
      float sum = 0.f;
#pragma unroll
      for (int nt = 0; nt < 4; nt++) {
        p[nt][j] = __expf(s[nt][j] * scale - m_new);
        sum += p[nt][j];
      }
#pragma unroll
      for (int off = 1; off < 16; off <<= 1) sum += __shfl_xor(sum, off);
      l_run[j] = l_run[j] * alpha + sum;
      m_run[j] = m_new;
#pragma unroll
      for (int nt2 = 0; nt2 < 4; nt2++) oacc[nt2][j] *= alpha;
    }

#pragma unroll
    for (int nt = 0; nt < 4; nt++)
#pragma unroll
      for (int j = 0; j < 4; j++)
        Ps[w][((lane >> 4) * 4 + j) * 64 + nt * 16 + (lane & 15)] = f2bf(p[nt][j]);

    bf16x8 pa[2];
#pragma unroll
    for (int t = 0; t < 2; t++)
      pa[t] = *(const bf16x8*)&Ps[w][(lane & 15) * 64 + t * 32 + (lane >> 4) * 8];
#pragma unroll
    for (int nt2 = 0; nt2 < 4; nt2++) {
#pragma unroll
      for (int t = 0; t < 2; t++) {
        bf16x8 vf =
            *(const bf16x8*)&Vs[cur][(nt2 * 16 + (lane & 15)) * 64 + t * 32 + (lane >> 4) * 8];
        oacc[nt2] = __builtin_amdgcn_mfma_f32_16x16x32_bf16(pa[t], vf, oacc[nt2], 0, 0, 0);
      }
    }
    __syncthreads();
  }

#pragma unroll
  for (int nt2 = 0; nt2 < 4; nt2++) {
#pragma unroll
    for (int j = 0; j < 4; j++) {
      int q = qt * 64 + w * 16 + (lane >> 4) * 4 + j;
      float v = oacc[nt2][j] / l_run[j];
      o[((size_t)(b * Nn_ + q)) * Cc + h * 64 + nt2 * 16 + (lane & 15)] = f2bf(v);
    }
  }
#undef STAGE_KV
}

extern "C" void kernel_launch(void* const* d_in, const int* in_sizes, int n_in,
                              void* d_out, int out_size, void* d_ws, size_t ws_size,
                              hipStream_t stream) {
  const float* x = (const float*)d_in[0];
  const float* cache_k = (const float*)d_in[1];
  const float* cache_v = (const float*)d_in[2];
  const float* qkv_w = (const float*)d_in[3];
  const float* qkv_b = (const float*)d_in[4];
  const float* proj_w = (const float*)d_in[5];
  const float* proj_b = (const float*)d_in[6];
  const float* n1w = (const float*)d_in[7];
  const float* n1b = (const float*)d_in[8];
  const float* n2w = (const float*)d_in[9];
  const float* n2b = (const float*)d_in[10];
  const float* fc1w = (const float*)d_in[11];
  const float* fc1b = (const float*)d_in[12];
  const float* fc2w = (const float*)d_in[13];
  const float* fc2b = (const float*)d_in[14];

  char* ws = (char*)d_ws;
  unsigned short* wq_t = (unsigned short*)(ws + 0);          //  [3072][1024]
  unsigned short* wp_t = (unsigned short*)(ws + 6291456);    //  [1024][1024]
  unsigned short* w1_t = (unsigned short*)(ws + 8388608);    //  [4096][1024]
  unsigned short* w2_t = (unsigned short*)(ws + 16777216);   //  [1024][4096]
  float* x2           = (float*)(ws + 25165824);             //  [9216][1024] f32
  unsigned short* obuf = (unsigned short*)(ws + 62914560);   //  [9216][1024]
  unsigned short* hbuf = (unsigned short*)(ws + 81788928);   //  [9216][1024]
  unsigned short* vt   = (unsigned short*)(ws + 100663296);  //  [256][64][832]
  unsigned short* qkvb = (unsigned short*)(ws + 127926272);  //  [9216][3072]
  unsigned short* kg   = (unsigned short*)(ws + 184549376);  //  [256][832][64]
  unsigned short* midb = qkvb;  // fc1 out [9216][4096]; overruns into kg (dead by then)

  hipFuncSetAttribute((const void*)&gemm8_k<0>, hipFuncAttributeMaxDynamicSharedMemorySize, 131072);
  hipFuncSetAttribute((const void*)&gemm8_k<2>, hipFuncAttributeMaxDynamicSharedMemorySize, 131072);
  hipFuncSetAttribute((const void*)&gemmD_k<1>, hipFuncAttributeMaxDynamicSharedMemorySize, 65536);
  hipFuncSetAttribute((const void*)&gemmD_k<2>, hipFuncAttributeMaxDynamicSharedMemorySize, 65536);

  wtrans2_k<<<dim3(16, 48), 256, 0, stream>>>(qkv_w, wq_t, 1024, 3072);
  wtrans2_k<<<dim3(16, 16), 256, 0, stream>>>(proj_w, wp_t, 1024, 1024);
  wtrans2_k<<<dim3(16, 64), 256, 0, stream>>>(fc1w, w1_t, 1024, 4096);
  wtrans2_k<<<dim3(64, 16), 256, 0, stream>>>(fc2w, w2_t, 4096, 1024);

  ln_k<<<ROWS, 256, 0, stream>>>(x, n1w, n1b, hbuf);
  gemm8_k<0><<<dim3(36, 12), 512, 131072, stream>>>(hbuf, wq_t, qkv_b, nullptr, qkvb, 3072, 1024);

  gatherk_k<<<dim3(208, 256), 256, 0, stream>>>(qkvb, cache_k, kg);
  gathervt_k<<<dim3(26, 2, 256), dim3(32, 8), 0, stream>>>(qkvb, cache_v, vt);
  attn_k<<<dim3(9, 256), 256, 0, stream>>>(qkvb, kg, vt, obuf);

  gemm8_k<2><<<dim3(36, 4), 512, 131072, stream>>>(obuf, wp_t, proj_b, x, x2, 1024, 1024);
  ln_k<<<ROWS, 256, 0, stream>>>(x2, n2w, n2b, hbuf);

  // A/B: FC1 + FC2 on the 2-blocks/CU pipelined 128^2 variant
  gemmD_k<1><<<dim3(72, 32), 256, 65536, stream>>>(hbuf, w1_t, fc1b, nullptr, midb, 4096, 1024);
  gemmD_k<2><<<dim3(72, 8), 256, 65536, stream>>>(midb, w2_t, fc2b, x2, (float*)d_out, 1024, 4096);
}

// Round 13
// 528.498 us; speedup vs baseline: 6.2447x; 1.0636x over previous
//
#include <hip/hip_runtime.h>

// Problem constants
#define Bb 16
#define Nn_ 576
#define Cc 1024
#define Hh 16
#define HD 64
#define HID 4096
#define AVAIL 832   // CUR(256) + N(576)
#define ROWS (Bb*Nn_)  // 9216

typedef __bf16 bf16x8 __attribute__((ext_vector_type(8)));
typedef float f32x4 __attribute__((ext_vector_type(4)));

__device__ __forceinline__ unsigned short f2bf(float f) {
  unsigned u = __float_as_uint(f);
  u += 0x7FFF + ((u >> 16) & 1);
  return (unsigned short)(u >> 16);
}

__device__ __forceinline__ void glds16(const void* g, void* l) {
  __builtin_amdgcn_global_load_lds(
      (const __attribute__((address_space(1))) void*)g,
      (__attribute__((address_space(3))) void*)l, 16, 0, 0);
}

__device__ __forceinline__ bf16x8 ds_read128(const void* p) {
  bf16x8 r;
  asm volatile("ds_read_b128 %0, %1"
               : "=v"(r)
               : "v"((const __attribute__((address_space(3))) char*)p));
  return r;
}

#define BARR() asm volatile("s_barrier" ::: "memory")
#define VMCNT8() asm volatile("s_waitcnt vmcnt(8)" ::: "memory")
#define VMCNT0() asm volatile("s_waitcnt vmcnt(0)" ::: "memory")
#define LGKM0() asm volatile("s_waitcnt lgkmcnt(0)" ::: "memory")
#define SCHEDB() __builtin_amdgcn_sched_barrier(0)

// ---------------- weight convert+transpose: in [K][N] f32 -> out [N][K] bf16
// 64x64 tiles, 16B stores (full-line writes; avoids write-allocate overfetch)
__global__ void wtrans2_k(const float* __restrict__ in, unsigned short* __restrict__ out,
                          int K, int N) {
  __shared__ float tile[64][65];
  int k0 = blockIdx.x * 64, n0 = blockIdx.y * 64;
  int tid = threadIdx.x;  // 256
  int nl = tid & 63, kl0 = tid >> 6;
#pragma unroll
  for (int j = 0; j < 16; j++) {
    int kl = kl0 + j * 4;
    tile[nl][kl] = in[(size_t)(k0 + kl) * N + n0 + nl];
  }
  __syncthreads();
  int no0 = tid >> 3, ko = (tid & 7) * 8;
#pragma unroll
  for (int i = 0; i < 2; i++) {
    int no = no0 + i * 32;
    const float* tp = &tile[no][ko];
    ushort4 oa, ob;
    oa.x = f2bf(tp[0]); oa.y = f2bf(tp[1]); oa.z = f2bf(tp[2]); oa.w = f2bf(tp[3]);
    ob.x = f2bf(tp[4]); ob.y = f2bf(tp[5]); ob.z = f2bf(tp[6]); ob.w = f2bf(tp[7]);
    unsigned short* op = &out[(size_t)(n0 + no) * K + k0 + ko];
    *(ushort4*)op = oa;
    *(ushort4*)(op + 4) = ob;
  }
}

// ---------------- LayerNorm f32 -> bf16, one block per row of 1024
__global__ void ln_k(const float* __restrict__ x, const float* __restrict__ w,
                     const float* __restrict__ bi, unsigned short* __restrict__ out) {
  int row = blockIdx.x;
  int t = threadIdx.x;
  float4 v = ((const float4*)(x + (size_t)row * Cc))[t];
  float s = v.x + v.y + v.z + v.w;
  float s2 = v.x * v.x + v.y * v.y + v.z * v.z + v.w * v.w;
#pragma unroll
  for (int off = 1; off < 64; off <<= 1) { s += __shfl_xor(s, off); s2 += __shfl_xor(s2, off); }
  __shared__ float red[8];
  int wid = t >> 6, lane = t & 63;
  if (lane == 0) { red[wid] = s; red[4 + wid] = s2; }
  __syncthreads();
  s = red[0] + red[1] + red[2] + red[3];
  s2 = red[4] + red[5] + red[6] + red[7];
  float mean = s * (1.0f / Cc);
  float var = s2 * (1.0f / Cc) - mean * mean;
  float rstd = rsqrtf(var + 1e-5f);
  float4 wv = ((const float4*)w)[t];
  float4 bv = ((const float4*)bi)[t];
  ushort4 ov;
  ov.x = f2bf((v.x - mean) * rstd * wv.x + bv.x);
  ov.y = f2bf((v.y - mean) * rstd * wv.y + bv.y);
  ov.z = f2bf((v.z - mean) * rstd * wv.z + bv.z);
  ov.w = f2bf((v.w - mean) * rstd * wv.w + bv.w);
  *(ushort4*)(out + (size_t)row * Cc + t * 4) = ov;
}

// ---------------- gemmD_k: 128x128 tile, 4 waves, BK=64, double-buffered
// 64KB LDS -> 2 blocks/CU co-resident + counted vmcnt(8) pipeline.
// R12 A/B proved this beats the 256^2 1-block/CU variant: cross-block overlap
// (m114) supplies the latency hiding no intra-block schedule could.
// EPI: 0 bf16, 1 gelu->bf16, 2 f32+resid
template <int EPI>
__global__ __launch_bounds__(256, 2) void gemmD_k(
    const unsigned short* __restrict__ A, const unsigned short* __restrict__ Bt,
    const float* __restrict__ bias, const float* __restrict__ resid,
    void* __restrict__ outv, int N, int K) {
  extern __shared__ __align__(16) char smem[];
  char* A0buf = smem;            // 16KB each
  char* B0buf = smem + 16384;
  char* A1buf = smem + 32768;
  char* B1buf = smem + 49152;

  const int tid = threadIdx.x, lane = tid & 63, wid = tid >> 6;
  const int wr = wid >> 1, wc = wid & 1;
  const int l15 = lane & 15, l4 = lane >> 4;
  const int m0 = blockIdx.x * 128, n0 = blockIdx.y * 128;
  const int KT = K >> 6;
  const size_t K2 = (size_t)K * 2;

  const int toff = (tid >> 3) * (int)K2 + ((((tid & 7) ^ ((tid >> 3) & 7)) << 4));
  const char* AsD = (const char*)A + (size_t)m0 * K2 + toff;
  const char* BsD = (const char*)Bt + (size_t)n0 * K2 + toff;
  const size_t l32 = 32 * K2;
  const int dst = tid * 16;

  const int s0 = ((l4 ^ (l15 & 7)) << 4);
  const int rbA = (wr * 64 + l15) * 128;
  const int rbB = (wc * 64 + l15) * 128;

  f32x4 acc[4][4] = {};
  bf16x8 av[4][2], bv[4][2];

#define DSTAGE(src, ktb, ldsT)                  \
  do {                                          \
    const char* _g = (src) + (size_t)(ktb);     \
    glds16(_g, (ldsT) + dst);                   \
    glds16(_g + l32, (ldsT) + 4096 + dst);      \
    glds16(_g + 2 * l32, (ldsT) + 8192 + dst);  \
    glds16(_g + 3 * l32, (ldsT) + 12288 + dst); \
  } while (0)

#define DRD(CA, CB)                                                          \
  do {                                                                       \
    _Pragma("unroll") for (int mi = 0; mi < 4; ++mi)                         \
    _Pragma("unroll") for (int ks = 0; ks < 2; ++ks)                         \
      av[mi][ks] = ds_read128((CA) + rbA + mi * 2048 + (s0 ^ (ks << 6)));    \
    _Pragma("unroll") for (int ni = 0; ni < 4; ++ni)                         \
    _Pragma("unroll") for (int ks = 0; ks < 2; ++ks)                         \
      bv[ni][ks] = ds_read128((CB) + rbB + ni * 2048 + (s0 ^ (ks << 6)));    \
  } while (0)

#define DMF()                                                                \
  _Pragma("unroll") for (int mi = 0; mi < 4; ++mi)                           \
  _Pragma("unroll") for (int ni = 0; ni < 4; ++ni)                           \
  _Pragma("unroll") for (int ks = 0; ks < 2; ++ks)                           \
    acc[mi][ni] = __builtin_amdgcn_mfma_f32_16x16x32_bf16(                   \
        av[mi][ks], bv[ni][ks], acc[mi][ni], 0, 0, 0);

  // prologue: tiles 0 and 1 (8 loads each); drain tile0, keep tile1 flying
  DSTAGE(AsD, 0, A0buf);
  DSTAGE(BsD, 0, B0buf);
  DSTAGE(AsD, 128, A1buf);
  DSTAGE(BsD, 128, B1buf);
  VMCNT8();
  BARR();

#pragma unroll 1
  for (int t = 0; t + 3 < KT; t += 2) {
    // tile t (buf0): read; barrier; stage t+2 into buf0; MFMA; vmcnt(8)=t+1 landed
    DRD(A0buf, B0buf);
    LGKM0(); SCHEDB(); BARR();
    DSTAGE(AsD, (size_t)(t + 2) * 128, A0buf);
    DSTAGE(BsD, (size_t)(t + 2) * 128, B0buf);
    __builtin_amdgcn_s_setprio(1); DMF(); __builtin_amdgcn_s_setprio(0);
    VMCNT8(); BARR();
    // tile t+1 (buf1)
    DRD(A1buf, B1buf);
    LGKM0(); SCHEDB(); BARR();
    DSTAGE(AsD, (size_t)(t + 3) * 128, A1buf);
    DSTAGE(BsD, (size_t)(t + 3) * 128, B1buf);
    __builtin_amdgcn_s_setprio(1); DMF(); __builtin_amdgcn_s_setprio(0);
    VMCNT8(); BARR();
  }
  // tile KT-2 (buf0): no stage; drain tile KT-1's loads
  DRD(A0buf, B0buf);
  LGKM0(); SCHEDB(); BARR();
  __builtin_amdgcn_s_setprio(1); DMF(); __builtin_amdgcn_s_setprio(0);
  VMCNT0(); BARR();
  // tile KT-1 (buf1): pure compute
  DRD(A1buf, B1buf);
  LGKM0(); SCHEDB();
  DMF();

  // coalesced epilogue via per-wave 8KB LDS scratch (buf0 region; buf1 untouched)
  BARR();
  {
    float* eb = (float*)(smem + wid * 8192);
    const int gc0 = n0 + wc * 64;
    const f32x4 bv4 = *(const f32x4*)&bias[gc0 + l15 * 4];
#pragma unroll
    for (int mi = 0; mi < 4; mi++) {
#pragma unroll
      for (int ni = 0; ni < 4; ni++)
#pragma unroll
        for (int j = 0; j < 4; j++)
          eb[(l4 * 4 + j) * 68 + ni * 16 + l15] = acc[mi][ni][j];
      int gr0 = m0 + wr * 64 + mi * 16;
#pragma unroll
      for (int k = 0; k < 4; k++) {
        int r = k * 4 + l4;
        f32x4 v = *(const f32x4*)&eb[r * 68 + l15 * 4];
        v += bv4;
        size_t base = (size_t)(gr0 + r) * N + gc0 + l15 * 4;
        if (EPI == 1) {
#pragma unroll
          for (int q = 0; q < 4; q++)
            v[q] = 0.5f * v[q] * (1.0f + erff(v[q] * 0.70710678118f));
        }
        if (EPI == 2) {
          f32x4 rv = *(const f32x4*)&resid[base];
          *(f32x4*)((float*)outv + base) = v + rv;
        } else {
          ushort4 o4;
          o4.x = f2bf(v[0]); o4.y = f2bf(v[1]); o4.z = f2bf(v[2]); o4.w = f2bf(v[3]);
          *(ushort4*)((unsigned short*)outv + base) = o4;
        }
      }
    }
  }
#undef DMF
#undef DRD
#undef DSTAGE
}

// ---------------- gather K: Kg[bh][p][d] (bf16) from qkv + cache_k
__global__ void gatherk_k(const unsigned short* __restrict__ qkv,
                          const float* __restrict__ cache_k,
                          unsigned short* __restrict__ Kg) {
  int bh = blockIdx.y, b = bh >> 4, h = bh & 15;
  int p = blockIdx.x * 4 + (threadIdx.x >> 6);
  int d = threadIdx.x & 63;
  unsigned short val;
  if (p < 64)
    val = qkv[((size_t)(b * Nn_ + p)) * 3072 + 1024 + h * 64 + d];
  else if (p < 320)
    val = f2bf(cache_k[(((size_t)b * Hh + h) * 1024 + p) * 64 + d]);
  else
    val = qkv[((size_t)(b * Nn_ + p - 256)) * 3072 + 1024 + h * 64 + d];
  Kg[(((size_t)bh) * AVAIL + p) * 64 + d] = val;
}

// ---------------- gather V transposed: Vt[bh][d][p] (bf16)
__global__ void gathervt_k(const unsigned short* __restrict__ qkv,
                           const float* __restrict__ cache_v,
                           unsigned short* __restrict__ Vt) {
  __shared__ float tile[32][33];
  int bh = blockIdx.z, b = bh >> 4, h = bh & 15;
  int p0 = blockIdx.x * 32, d0 = blockIdx.y * 32;
  int tx = threadIdx.x, ty = threadIdx.y;  // 32 x 8
#pragma unroll
  for (int i = 0; i < 4; i++) {
    int p = p0 + ty + i * 8, d = d0 + tx;
    float v;
    if (p < 64)
      v = __uint_as_float((unsigned)qkv[((size_t)(b * Nn_ + p)) * 3072 + 2048 + h * 64 + d] << 16);
    else if (p < 320)
      v = cache_v[(((size_t)b * Hh + h) * 1024 + p) * 64 + d];
    else
      v = __uint_as_float((unsigned)qkv[((size_t)(b * Nn_ + p - 256)) * 3072 + 2048 + h * 64 + d] << 16);
    tile[ty + i * 8][tx] = v;
  }
  __syncthreads();
#pragma unroll
  for (int i = 0; i < 4; i++)
    Vt[(((size_t)bh) * 64 + d0 + ty + i * 8) * AVAIL + p0 + tx] = f2bf(tile[tx][ty + i * 8]);
}

// ---------------- flash attention (double-buffered K/V chunks)
__global__ __launch_bounds__(256) void attn_k(
    const unsigned short* __restrict__ qkv, const unsigned short* __restrict__ Kg,
    const unsigned short* __restrict__ Vt, unsigned short* __restrict__ o) {
  __shared__ __attribute__((aligned(16))) unsigned short Qs[64 * 64];
  __shared__ __attribute__((aligned(16))) unsigned short Ks[2][64 * 64];
  __shared__ __attribute__((aligned(16))) unsigned short Vs[2][64 * 64];
  __shared__ __attribute__((aligned(16))) unsigned short Ps[4][16 * 64];

  const int tid = threadIdx.x;
  const int lane = tid & 63;
  const int w = tid >> 6;
  const int qt = blockIdx.x;
  const int bh = blockIdx.y, b = bh >> 4, h = bh & 15;
  const float scale = 0.125f;

  const char* kbase = (const char*)(Kg + (size_t)bh * AVAIL * 64);
  const char* vbase = (const char*)(Vt + (size_t)bh * 64 * AVAIL);
  const int vr = tid >> 3;
  const int vcb = (tid & 7) << 4;

#define STAGE_KV(c, buf)                                                          \
  do {                                                                            \
    glds16(kbase + (size_t)(c) * 8192 + tid * 16, (char*)Ks[buf] + tid * 16);     \
    glds16(kbase + (size_t)(c) * 8192 + 4096 + tid * 16,                          \
           (char*)Ks[buf] + 4096 + tid * 16);                                     \
    glds16(vbase + (size_t)vr * (AVAIL * 2) + (c) * 128 + vcb,                    \
           (char*)Vs[buf] + tid * 16);                                            \
    glds16(vbase + (size_t)(vr + 32) * (AVAIL * 2) + (c) * 128 + vcb,             \
           (char*)Vs[buf] + 4096 + tid * 16);                                     \
  } while (0)

  {
    const char* qb = (const char*)qkv;
    glds16(qb + ((size_t)(b * Nn_ + qt * 64 + vr) * 3072 + h * 64) * 2 + vcb,
           (char*)Qs + tid * 16);
    glds16(qb + ((size_t)(b * Nn_ + qt * 64 + 32 + vr) * 3072 + h * 64) * 2 + vcb,
           (char*)Qs + 4096 + tid * 16);
  }
  STAGE_KV(0, 0);
  asm volatile("s_waitcnt vmcnt(0)" ::: "memory");
  __syncthreads();

  bf16x8 qf[2];
#pragma unroll
  for (int t = 0; t < 2; t++)
    qf[t] = *(const bf16x8*)&Qs[(w * 16 + (lane & 15)) * 64 + t * 32 + (lane >> 4) * 8];

  float m_run[4], l_run[4];
  f32x4 oacc[4] = {};
#pragma unroll
  for (int j = 0; j < 4; j++) { m_run[j] = -1e30f; l_run[j] = 0.f; }

  for (int c = 0; c < 13; c++) {
    const int cur = c & 1;
    if (c < 12) STAGE_KV(c + 1, cur ^ 1);

    f32x4 s[4] = {};
#pragma unroll
    for (int nt = 0; nt < 4; nt++) {
#pragma unroll
      for (int t = 0; t < 2; t++) {
        bf16x8 kf =
            *(const bf16x8*)&Ks[cur][(nt * 16 + (lane & 15)) * 64 + t * 32 + (lane >> 4) * 8];
        s[nt] = __builtin_amdgcn_mfma_f32_16x16x32_bf16(qf[t], kf, s[nt], 0, 0, 0);
      }
    }

    float p[4][4];
#pragma unroll
    for (int j = 0; j < 4; j++) {
      float mx = fmaxf(fmaxf(s[0][j], s[1][j]), fmaxf(s[2][j], s[3][j])) * scale;
#pragma unroll
      for (int off = 1; off < 16; off <<= 1) mx = fmaxf(mx, __shfl_xor(mx, off));
      float m_new = fmaxf(m_run[j], mx);
      float alpha = __expf(m_run[j] - m_new);
      float sum = 0.f;
#pragma unroll
      for (int nt = 0; nt < 4; nt++) {
        p[nt][j] = __expf(s[nt][j] * scale - m_new);
        sum += p[nt][j];
      }
#pragma unroll
      for (int off = 1; off < 16; off <<= 1) sum += __shfl_xor(sum, off);
      l_run[j] = l_run[j] * alpha + sum;
      m_run[j] = m_new;
#pragma unroll
      for (int nt2 = 0; nt2 < 4; nt2++) oacc[nt2][j] *= alpha;
    }

#pragma unroll
    for (int nt = 0; nt < 4; nt++)
#pragma unroll
      for (int j = 0; j < 4; j++)
        Ps[w][((lane >> 4) * 4 + j) * 64 + nt * 16 + (lane & 15)] = f2bf(p[nt][j]);

    bf16x8 pa[2];
#pragma unroll
    for (int t = 0; t < 2; t++)
      pa[t] = *(const bf16x8*)&Ps[w][(lane & 15) * 64 + t * 32 + (lane >> 4) * 8];
#pragma unroll
    for (int nt2 = 0; nt2 < 4; nt2++) {
#pragma unroll
      for (int t = 0; t < 2; t++) {
        bf16x8 vf =
            *(const bf16x8*)&Vs[cur][(nt2 * 16 + (lane & 15)) * 64 + t * 32 + (lane >> 4) * 8];
        oacc[nt2] = __builtin_amdgcn_mfma_f32_16x16x32_bf16(pa[t], vf, oacc[nt2], 0, 0, 0);
      }
    }
    __syncthreads();
  }

#pragma unroll
  for (int nt2 = 0; nt2 < 4; nt2++) {
#pragma unroll
    for (int j = 0; j < 4; j++) {
      int q = qt * 64 + w * 16 + (lane >> 4) * 4 + j;
      float v = oacc[nt2][j] / l_run[j];
      o[((size_t)(b * Nn_ + q)) * Cc + h * 64 + nt2 * 16 + (lane & 15)] = f2bf(v);
    }
  }
#undef STAGE_KV
}

extern "C" void kernel_launch(void* const* d_in, const int* in_sizes, int n_in,
                              void* d_out, int out_size, void* d_ws, size_t ws_size,
                              hipStream_t stream) {
  const float* x = (const float*)d_in[0];
  const float* cache_k = (const float*)d_in[1];
  const float* cache_v = (const float*)d_in[2];
  const float* qkv_w = (const float*)d_in[3];
  const float* qkv_b = (const float*)d_in[4];
  const float* proj_w = (const float*)d_in[5];
  const float* proj_b = (const float*)d_in[6];
  const float* n1w = (const float*)d_in[7];
  const float* n1b = (const float*)d_in[8];
  const float* n2w = (const float*)d_in[9];
  const float* n2b = (const float*)d_in[10];
  const float* fc1w = (const float*)d_in[11];
  const float* fc1b = (const float*)d_in[12];
  const float* fc2w = (const float*)d_in[13];
  const float* fc2b = (const float*)d_in[14];

  char* ws = (char*)d_ws;
  unsigned short* wq_t = (unsigned short*)(ws + 0);          //  [3072][1024]
  unsigned short* wp_t = (unsigned short*)(ws + 6291456);    //  [1024][1024]
  unsigned short* w1_t = (unsigned short*)(ws + 8388608);    //  [4096][1024]
  unsigned short* w2_t = (unsigned short*)(ws + 16777216);   //  [1024][4096]
  float* x2           = (float*)(ws + 25165824);             //  [9216][1024] f32
  unsigned short* obuf = (unsigned short*)(ws + 62914560);   //  [9216][1024]
  unsigned short* hbuf = (unsigned short*)(ws + 81788928);   //  [9216][1024]
  unsigned short* vt   = (unsigned short*)(ws + 100663296);  //  [256][64][832]
  unsigned short* qkvb = (unsigned short*)(ws + 127926272);  //  [9216][3072]
  unsigned short* kg   = (unsigned short*)(ws + 184549376);  //  [256][832][64]
  unsigned short* midb = qkvb;  // fc1 out [9216][4096]; overruns into kg (dead by then)

  hipFuncSetAttribute((const void*)&gemmD_k<0>, hipFuncAttributeMaxDynamicSharedMemorySize, 65536);
  hipFuncSetAttribute((const void*)&gemmD_k<1>, hipFuncAttributeMaxDynamicSharedMemorySize, 65536);
  hipFuncSetAttribute((const void*)&gemmD_k<2>, hipFuncAttributeMaxDynamicSharedMemorySize, 65536);

  wtrans2_k<<<dim3(16, 48), 256, 0, stream>>>(qkv_w, wq_t, 1024, 3072);
  wtrans2_k<<<dim3(16, 16), 256, 0, stream>>>(proj_w, wp_t, 1024, 1024);
  wtrans2_k<<<dim3(16, 64), 256, 0, stream>>>(fc1w, w1_t, 1024, 4096);
  wtrans2_k<<<dim3(64, 16), 256, 0, stream>>>(fc2w, w2_t, 4096, 1024);

  ln_k<<<ROWS, 256, 0, stream>>>(x, n1w, n1b, hbuf);
  gemmD_k<0><<<dim3(72, 24), 256, 65536, stream>>>(hbuf, wq_t, qkv_b, nullptr, qkvb, 3072, 1024);

  gatherk_k<<<dim3(208, 256), 256, 0, stream>>>(qkvb, cache_k, kg);
  gathervt_k<<<dim3(26, 2, 256), dim3(32, 8), 0, stream>>>(qkvb, cache_v, vt);
  attn_k<<<dim3(9, 256), 256, 0, stream>>>(qkvb, kg, vt, obuf);

  gemmD_k<2><<<dim3(72, 8), 256, 65536, stream>>>(obuf, wp_t, proj_b, x, x2, 1024, 1024);
  ln_k<<<ROWS, 256, 0, stream>>>(x2, n2w, n2b, hbuf);

  gemmD_k<1><<<dim3(72, 32), 256, 65536, stream>>>(hbuf, w1_t, fc1b, nullptr, midb, 4096, 1024);
  gemmD_k<2><<<dim3(72, 8), 256, 65536, stream>>>(midb, w2_t, fc2b, x2, (float*)d_out, 1024, 4096);
}